// Round 1
// baseline (1173.860 us; speedup 1.0000x reference)
//
#include <hip/hip_runtime.h>

// Qwen2 MoE block for MI355X (gfx950).
// Sizes fixed per reference:
#define T_TOK 2048
#define NE 16
#define KTOP 4
#define HD 2048
#define ID 1408
#define SID 5632
#define CAPACITY 1024

typedef __attribute__((ext_vector_type(8))) short short8;   // 8 x bf16 (4 VGPR) MFMA operand
typedef __attribute__((ext_vector_type(4))) float floatx4;  // MFMA accumulator

// fp32 -> bf16 round-to-nearest-even (finite inputs)
__device__ __forceinline__ short f2b(float f){
  union { float f; unsigned u; } v; v.f = f;
  unsigned r = v.u + 0x7fffu + ((v.u >> 16) & 1u);
  return (short)(r >> 16);
}

// LDS tile layout: [row][32 k] bf16 = 64B/row, 4x 16B slots per row.
// XOR-swizzle the slot with (row>>1)&3 -> b128 fragment reads are 2-way (free).
__device__ __forceinline__ int ldsoff(int row, int slot){
  return (row << 6) + (((slot ^ (row >> 1)) & 3) << 4);
}

__global__ void moe_zero(int* __restrict__ counts){
  if (threadIdx.x < NE) counts[threadIdx.x] = 0;
}

// Router: logits (fp32 exact) -> d_out tail; softmax+top4; slot assignment via
// atomics (order-free: no drops at CAP=2x mean load); x -> bf16; shared-gate dot.
__global__ void moe_router(const float* __restrict__ x,
                           const float* __restrict__ gate_w,
                           const float* __restrict__ sg_w,
                           float* __restrict__ logits_out,
                           short* __restrict__ xb,
                           int* __restrict__ counts,
                           int* __restrict__ slot_token,
                           float* __restrict__ slot_w,
                           float* __restrict__ sg)
{
  int wave = threadIdx.x >> 6;
  int lane = threadIdx.x & 63;
  int t = (blockIdx.x << 2) + wave;
  if (t >= T_TOK) return;
  const float* xr = x + (size_t)t * HD;
  float acc[17];
  #pragma unroll
  for (int e = 0; e < 17; ++e) acc[e] = 0.f;
  for (int j = 0; j < HD / 64; ++j){
    int h = (j << 6) + lane;
    float xv = xr[h];
    xb[(size_t)t * HD + h] = f2b(xv);
    #pragma unroll
    for (int e = 0; e < 16; ++e) acc[e] += xv * gate_w[e * HD + h];
    acc[16] += xv * sg_w[h];
  }
  #pragma unroll
  for (int e = 0; e < 17; ++e){
    float v = acc[e];
    #pragma unroll
    for (int off = 32; off > 0; off >>= 1) v += __shfl_xor(v, off, 64);
    acc[e] = v;
  }
  if (lane == 0){
    float m = acc[0];
    #pragma unroll
    for (int e = 1; e < 16; ++e) m = fmaxf(m, acc[e]);
    float p[16]; float s = 0.f;
    #pragma unroll
    for (int e = 0; e < 16; ++e){ p[e] = expf(acc[e] - m); s += p[e]; }
    float inv = 1.f / s;
    #pragma unroll
    for (int e = 0; e < 16; ++e) logits_out[t * 16 + e] = acc[e];
    unsigned used = 0;
    for (int k = 0; k < KTOP; ++k){
      float best = -1.f; int bi = 0;
      #pragma unroll
      for (int e = 0; e < 16; ++e){
        float pe = ((used >> e) & 1u) ? -1.f : p[e];
        if (pe > best){ best = pe; bi = e; }
      }
      used |= (1u << bi);
      int pos = atomicAdd(&counts[bi], 1);
      if (pos < CAPACITY){
        slot_token[bi * CAPACITY + pos] = t;
        slot_w[bi * CAPACITY + pos] = best * inv;
      }
    }
    sg[t] = 1.f / (1.f + expf(-acc[16]));
  }
}

// Fused gate+up GEMM (dual accumulators share the A tile), SiLU(g)*u -> bf16 out.
// Tile: BM=128, BN=64, BK=32. 4 waves as 2(m)x2(n); wave = 64m x 32n (4x2 frags x2).
// A: bf16 rows (gathered via slot_token in expert mode). B: fp32 [N][K] weights,
// converted to bf16 in registers during staging.
__global__ __launch_bounds__(256) void moe_gateup(
    const short* __restrict__ Asrc,
    const float* __restrict__ Wg,
    const float* __restrict__ Wu,
    short* __restrict__ Out,
    const int* __restrict__ counts,
    const int* __restrict__ slot_token,
    int Ndim, int Kdim, int expert_mode)
{
  int e = blockIdx.z;
  int cnt;
  const float* wg; const float* wu; short* out;
  if (expert_mode){
    cnt = counts[e]; if (cnt > CAPACITY) cnt = CAPACITY;
    if ((int)(blockIdx.x * 128) >= cnt) return;
    wg = Wg + (size_t)e * Ndim * Kdim;
    wu = Wu + (size_t)e * Ndim * Kdim;
    out = Out + (size_t)e * CAPACITY * Ndim;
  } else {
    cnt = T_TOK; wg = Wg; wu = Wu; out = Out;
  }
  const int m0 = blockIdx.x * 128;
  const int n0 = blockIdx.y * 64;

  __shared__ __align__(16) char smem[8192 + 4096 + 4096];
  char* sA  = smem;
  char* sBg = smem + 8192;
  char* sBu = smem + 12288;

  const int tid = threadIdx.x;
  const int lane = tid & 63, wave = tid >> 6;
  const int wr = wave >> 1, wc = wave & 1;
  const int lrow = lane & 15, lk = lane >> 4;

  // A staging: 2 threads/row, each 2x16B bf16 loads
  const int arow = tid >> 1, ahalf = tid & 1;
  const short* asrc;
  {
    int p = m0 + arow;
    if (expert_mode){
      int tok = slot_token[e * CAPACITY + ((p < cnt) ? p : 0)];
      asrc = Asrc + (size_t)tok * Kdim;
    } else {
      asrc = Asrc + (size_t)p * Kdim;
    }
  }
  // B staging: 4 threads/row (64 rows), each 2x float4 -> 1x b128
  const int brow = tid >> 2, bq = tid & 3;
  const float* bgr = wg + (size_t)(n0 + brow) * Kdim;
  const float* bur = wu + (size_t)(n0 + brow) * Kdim;

  const floatx4 vzero = {0.f, 0.f, 0.f, 0.f};
  floatx4 accg[4][2], accu[4][2];
  #pragma unroll
  for (int i = 0; i < 4; ++i)
    #pragma unroll
    for (int j = 0; j < 2; ++j){ accg[i][j] = vzero; accu[i][j] = vzero; }

  const int aoff0 = ldsoff(arow, ahalf * 2);
  const int aoff1 = ldsoff(arow, ahalf * 2 + 1);
  const int boff  = ldsoff(brow, bq);

  for (int k0 = 0; k0 < Kdim; k0 += 32){
    __syncthreads();
    short8 va0 = *(const short8*)(asrc + k0 + ahalf * 16);
    short8 va1 = *(const short8*)(asrc + k0 + ahalf * 16 + 8);
    *(short8*)(sA + aoff0) = va0;
    *(short8*)(sA + aoff1) = va1;
    {
      float4 f0 = *(const float4*)(bgr + k0 + bq * 8);
      float4 f1 = *(const float4*)(bgr + k0 + bq * 8 + 4);
      short8 vb = { f2b(f0.x), f2b(f0.y), f2b(f0.z), f2b(f0.w),
                    f2b(f1.x), f2b(f1.y), f2b(f1.z), f2b(f1.w) };
      *(short8*)(sBg + boff) = vb;
    }
    {
      float4 f0 = *(const float4*)(bur + k0 + bq * 8);
      float4 f1 = *(const float4*)(bur + k0 + bq * 8 + 4);
      short8 vb = { f2b(f0.x), f2b(f0.y), f2b(f0.z), f2b(f0.w),
                    f2b(f1.x), f2b(f1.y), f2b(f1.z), f2b(f1.w) };
      *(short8*)(sBu + boff) = vb;
    }
    __syncthreads();
    short8 a[4], bg[2], bu[2];
    #pragma unroll
    for (int mf = 0; mf < 4; ++mf)
      a[mf] = *(const short8*)(sA + ldsoff(wr * 64 + mf * 16 + lrow, lk));
    #pragma unroll
    for (int nf = 0; nf < 2; ++nf){
      bg[nf] = *(const short8*)(sBg + ldsoff(wc * 32 + nf * 16 + lrow, lk));
      bu[nf] = *(const short8*)(sBu + ldsoff(wc * 32 + nf * 16 + lrow, lk));
    }
    #pragma unroll
    for (int mf = 0; mf < 4; ++mf)
      #pragma unroll
      for (int nf = 0; nf < 2; ++nf){
        accg[mf][nf] = __builtin_amdgcn_mfma_f32_16x16x32_bf16(a[mf], bg[nf], accg[mf][nf], 0, 0, 0);
        accu[mf][nf] = __builtin_amdgcn_mfma_f32_16x16x32_bf16(a[mf], bu[nf], accu[mf][nf], 0, 0, 0);
      }
  }

  // epilogue: SiLU(g)*u -> bf16. C/D layout: col=lane&15, row=4*(lane>>4)+r.
  const int colbase = n0 + wc * 32 + lrow;
  #pragma unroll
  for (int mf = 0; mf < 4; ++mf){
    int pr = m0 + wr * 64 + mf * 16 + lk * 4;
    #pragma unroll
    for (int nf = 0; nf < 2; ++nf){
      floatx4 g4 = accg[mf][nf], u4 = accu[mf][nf];
      int col = colbase + nf * 16;
      #pragma unroll
      for (int r = 0; r < 4; ++r){
        float gv = g4[r], uv = u4[r];
        float a = (gv / (1.f + __expf(-gv))) * uv;
        out[(size_t)(pr + r) * Ndim + col] = f2b(a);
      }
    }
  }
}

// Down GEMM. Tile: BM=128, BN=128, BK=32; 4 waves 2x2, wave = 64x64 (4x4 frags).
// expert_mode: C rows -> atomicAdd into y[token] weighted by routing prob.
// shared mode: plain stores y = sigmoid_gate * C (runs BEFORE expert mode).
__global__ __launch_bounds__(256) void moe_down(
    const short* __restrict__ Asrc,
    const float* __restrict__ Wd,
    float* __restrict__ y,
    const int* __restrict__ counts,
    const int* __restrict__ slot_token,
    const float* __restrict__ slot_w,
    const float* __restrict__ sgate,
    int Kdim, int expert_mode)
{
  int e = blockIdx.z;
  int cnt; const short* ab; const float* wd;
  if (expert_mode){
    cnt = counts[e]; if (cnt > CAPACITY) cnt = CAPACITY;
    if ((int)(blockIdx.x * 128) >= cnt) return;
    ab = Asrc + (size_t)e * CAPACITY * Kdim;
    wd = Wd + (size_t)e * HD * Kdim;
  } else { cnt = T_TOK; ab = Asrc; wd = Wd; }
  const int m0 = blockIdx.x * 128, n0 = blockIdx.y * 128;

  __shared__ __align__(16) char smem[16384];
  char* sA = smem; char* sB = smem + 8192;

  const int tid = threadIdx.x;
  const int lane = tid & 63, wave = tid >> 6;
  const int wr = wave >> 1, wc = wave & 1;
  const int lrow = lane & 15, lk = lane >> 4;

  const int arow = tid >> 1, ahalf = tid & 1;
  const short* asrc = ab + (size_t)(m0 + arow) * Kdim;
  const int browi = tid >> 1, bhalf = tid & 1;
  const float* bsrc = wd + (size_t)(n0 + browi) * Kdim;

  const floatx4 vzero = {0.f, 0.f, 0.f, 0.f};
  floatx4 acc[4][4];
  #pragma unroll
  for (int i = 0; i < 4; ++i)
    #pragma unroll
    for (int j = 0; j < 4; ++j) acc[i][j] = vzero;

  const int aoff0 = ldsoff(arow, ahalf * 2);
  const int aoff1 = ldsoff(arow, ahalf * 2 + 1);
  const int boff0 = ldsoff(browi, bhalf * 2);
  const int boff1 = ldsoff(browi, bhalf * 2 + 1);

  for (int k0 = 0; k0 < Kdim; k0 += 32){
    __syncthreads();
    short8 va0 = *(const short8*)(asrc + k0 + ahalf * 16);
    short8 va1 = *(const short8*)(asrc + k0 + ahalf * 16 + 8);
    *(short8*)(sA + aoff0) = va0;
    *(short8*)(sA + aoff1) = va1;
    {
      float4 f0 = *(const float4*)(bsrc + k0 + bhalf * 16);
      float4 f1 = *(const float4*)(bsrc + k0 + bhalf * 16 + 4);
      float4 f2 = *(const float4*)(bsrc + k0 + bhalf * 16 + 8);
      float4 f3 = *(const float4*)(bsrc + k0 + bhalf * 16 + 12);
      short8 vb0 = { f2b(f0.x), f2b(f0.y), f2b(f0.z), f2b(f0.w),
                     f2b(f1.x), f2b(f1.y), f2b(f1.z), f2b(f1.w) };
      short8 vb1 = { f2b(f2.x), f2b(f2.y), f2b(f2.z), f2b(f2.w),
                     f2b(f3.x), f2b(f3.y), f2b(f3.z), f2b(f3.w) };
      *(short8*)(sB + boff0) = vb0;
      *(short8*)(sB + boff1) = vb1;
    }
    __syncthreads();
    short8 a[4], b[4];
    #pragma unroll
    for (int mf = 0; mf < 4; ++mf)
      a[mf] = *(const short8*)(sA + ldsoff(wr * 64 + mf * 16 + lrow, lk));
    #pragma unroll
    for (int nf = 0; nf < 4; ++nf)
      b[nf] = *(const short8*)(sB + ldsoff(wc * 64 + nf * 16 + lrow, lk));
    #pragma unroll
    for (int mf = 0; mf < 4; ++mf)
      #pragma unroll
      for (int nf = 0; nf < 4; ++nf)
        acc[mf][nf] = __builtin_amdgcn_mfma_f32_16x16x32_bf16(a[mf], b[nf], acc[mf][nf], 0, 0, 0);
  }

  const int colb = n0 + wc * 64 + lrow;
  if (expert_mode){
    #pragma unroll
    for (int mf = 0; mf < 4; ++mf){
      int pr = m0 + wr * 64 + mf * 16 + lk * 4;
      #pragma unroll
      for (int r = 0; r < 4; ++r){
        int p = pr + r;
        if (p < cnt){
          int tok = slot_token[e * CAPACITY + p];
          float w = slot_w[e * CAPACITY + p];
          #pragma unroll
          for (int nf = 0; nf < 4; ++nf)
            atomicAdd(&y[(size_t)tok * HD + colb + nf * 16], w * acc[mf][nf][r]);
        }
      }
    }
  } else {
    #pragma unroll
    for (int mf = 0; mf < 4; ++mf){
      int pr = m0 + wr * 64 + mf * 16 + lk * 4;
      #pragma unroll
      for (int r = 0; r < 4; ++r){
        int t = pr + r;
        float sv = sgate[t];
        #pragma unroll
        for (int nf = 0; nf < 4; ++nf)
          y[(size_t)t * HD + colb + nf * 16] = sv * acc[mf][nf][r];
      }
    }
  }
}

extern "C" void kernel_launch(void* const* d_in, const int* in_sizes, int n_in,
                              void* d_out, int out_size, void* d_ws, size_t ws_size,
                              hipStream_t stream)
{
  (void)in_sizes; (void)n_in; (void)out_size; (void)ws_size;
  const float* x       = (const float*)d_in[0];
  const float* gate_w  = (const float*)d_in[1];
  const float* we_gate = (const float*)d_in[2];
  const float* we_up   = (const float*)d_in[3];
  const float* we_down = (const float*)d_in[4];
  const float* wsg     = (const float*)d_in[5];
  const float* wsu     = (const float*)d_in[6];
  const float* wsd     = (const float*)d_in[7];
  const float* sg_w    = (const float*)d_in[8];

  float* y      = (float*)d_out;                       // [T, H]
  float* logits = y + (size_t)T_TOK * HD;              // [T, E]

  char* ws = (char*)d_ws;
  short* xb         = (short*)(ws);                    //  8,388,608 B: x as bf16 [T][H]
  short* act        = (short*)(ws + 8388608);          // 46,137,344 B: [E][CAP][I] bf16
  short* act_s      = (short*)(ws + 54525952);         // 23,068,672 B: [T][SI] bf16
  int*   slot_token = (int*)  (ws + 77594624);         //     65,536 B
  float* slot_w     = (float*)(ws + 77660160);         //     65,536 B
  int*   counts     = (int*)  (ws + 77725696);         //         64 B
  float* sg         = (float*)(ws + 77725760);         //      8,192 B

  moe_zero<<<1, 64, 0, stream>>>(counts);
  moe_router<<<512, 256, 0, stream>>>(x, gate_w, sg_w, logits, xb,
                                      counts, slot_token, slot_w, sg);
  // shared expert gate/up: M=2048 (16 mtiles), N=5632 (88 ntiles of 64), K=2048
  moe_gateup<<<dim3(16, 88, 1), 256, 0, stream>>>(xb, wsg, wsu, act_s,
                                                  nullptr, nullptr, SID, HD, 0);
  // expert gate/up: per-expert M<=1024 (8 mtiles max), N=1408 (22 ntiles), K=2048
  moe_gateup<<<dim3(8, 22, NE), 256, 0, stream>>>(xb, we_gate, we_up, act,
                                                  counts, slot_token, ID, HD, 1);
  // shared down (plain stores initialize y): M=2048, N=2048, K=5632
  moe_down<<<dim3(16, 16, 1), 256, 0, stream>>>(act_s, wsd, y,
                                                nullptr, nullptr, nullptr, sg, SID, 0);
  // expert down (atomic weighted combine): M<=1024, N=2048, K=1408
  moe_down<<<dim3(8, 16, NE), 256, 0, stream>>>(act, we_down, y,
                                                counts, slot_token, slot_w, nullptr, ID, 1);
}

// Round 2
// 913.337 us; speedup vs baseline: 1.2852x; 1.2852x over previous
//
#include <hip/hip_runtime.h>

#define T_TOK 2048
#define NE 16
#define KTOP 4
#define HD 2048
#define ID 1408
#define SID 5632
#define CAPACITY 1024

typedef __attribute__((ext_vector_type(8))) short short8;   // 8 x bf16
typedef __attribute__((ext_vector_type(4))) float floatx4;  // MFMA acc

// fp32 -> bf16 round-to-nearest-even
__device__ __forceinline__ short f2b(float f){
  union { float f; unsigned u; } v; v.f = f;
  unsigned r = v.u + 0x7fffu + ((v.u >> 16) & 1u);
  return (short)(r >> 16);
}

// async global->LDS, 16B per lane (wave-uniform LDS base + lane*16)
__device__ __forceinline__ void gl16(const void* g, void* l){
  __builtin_amdgcn_global_load_lds(
      (const __attribute__((address_space(1))) void*)g,
      (__attribute__((address_space(3))) void*)l, 16, 0, 0);
}

__global__ void moe_zero(int* __restrict__ counts){
  if (threadIdx.x < NE) counts[threadIdx.x] = 0;
}

// fp32 -> bf16 bulk weight conversion (8 elems / thread / iter)
__global__ void moe_convert(const float* __restrict__ src, short* __restrict__ dst, int n8){
  int stride = gridDim.x * blockDim.x;
  for (int i = blockIdx.x * blockDim.x + threadIdx.x; i < n8; i += stride){
    float4 f0 = ((const float4*)src)[(size_t)i * 2];
    float4 f1 = ((const float4*)src)[(size_t)i * 2 + 1];
    short8 v = { f2b(f0.x), f2b(f0.y), f2b(f0.z), f2b(f0.w),
                 f2b(f1.x), f2b(f1.y), f2b(f1.z), f2b(f1.w) };
    ((short8*)dst)[i] = v;
  }
}

// Router: fp32 logits -> d_out tail; softmax+top4; slot assignment via atomics
// (order-free: CAP = 2x mean load, drop prob ~0); x -> bf16; shared-gate sigmoid.
__global__ void moe_router(const float* __restrict__ x,
                           const float* __restrict__ gate_w,
                           const float* __restrict__ sg_w,
                           float* __restrict__ logits_out,
                           short* __restrict__ xb,
                           int* __restrict__ counts,
                           int* __restrict__ slot_token,
                           float* __restrict__ slot_w,
                           float* __restrict__ sg)
{
  int wave = threadIdx.x >> 6, lane = threadIdx.x & 63;
  int t = (blockIdx.x << 2) + wave;
  if (t >= T_TOK) return;
  const float4* xr = (const float4*)(x + (size_t)t * HD);
  short8* xbw = (short8*)(xb + (size_t)t * HD);
  float acc[17];
  #pragma unroll
  for (int e = 0; e < 17; ++e) acc[e] = 0.f;
  #pragma unroll
  for (int j = 0; j < 4; ++j){
    int i4 = (j * 64 + lane) * 2;
    float4 x0 = xr[i4], x1 = xr[i4 + 1];
    short8 v = { f2b(x0.x), f2b(x0.y), f2b(x0.z), f2b(x0.w),
                 f2b(x1.x), f2b(x1.y), f2b(x1.z), f2b(x1.w) };
    xbw[j * 64 + lane] = v;
    #pragma unroll
    for (int e = 0; e < 16; ++e){
      const float4* gr = (const float4*)(gate_w + e * HD);
      float4 g0 = gr[i4], g1 = gr[i4 + 1];
      acc[e] += x0.x*g0.x + x0.y*g0.y + x0.z*g0.z + x0.w*g0.w
              + x1.x*g1.x + x1.y*g1.y + x1.z*g1.z + x1.w*g1.w;
    }
    const float4* sr = (const float4*)sg_w;
    float4 s0 = sr[i4], s1 = sr[i4 + 1];
    acc[16] += x0.x*s0.x + x0.y*s0.y + x0.z*s0.z + x0.w*s0.w
             + x1.x*s1.x + x1.y*s1.y + x1.z*s1.z + x1.w*s1.w;
  }
  #pragma unroll
  for (int e = 0; e < 17; ++e){
    float v = acc[e];
    #pragma unroll
    for (int off = 32; off > 0; off >>= 1) v += __shfl_xor(v, off, 64);
    acc[e] = v;
  }
  if (lane == 0){
    float m = acc[0];
    #pragma unroll
    for (int e = 1; e < 16; ++e) m = fmaxf(m, acc[e]);
    float p[16]; float s = 0.f;
    #pragma unroll
    for (int e = 0; e < 16; ++e){ p[e] = expf(acc[e] - m); s += p[e]; }
    float inv = 1.f / s;
    #pragma unroll
    for (int e = 0; e < 16; ++e) logits_out[t * 16 + e] = acc[e];
    unsigned used = 0;
    for (int k = 0; k < KTOP; ++k){
      float best = -1.f; int bi = 0;
      #pragma unroll
      for (int e = 0; e < 16; ++e){
        float pe = ((used >> e) & 1u) ? -1.f : p[e];
        if (pe > best){ best = pe; bi = e; }
      }
      used |= (1u << bi);
      int pos = atomicAdd(&counts[bi], 1);
      if (pos < CAPACITY){
        slot_token[bi * CAPACITY + pos] = t;
        slot_w[bi * CAPACITY + pos] = best * inv;
      }
    }
    sg[t] = 1.f / (1.f + expf(-acc[16]));
  }
}

// ---------------------------------------------------------------------------
// GEMM tiles: BM=128, BK=64. LDS rows are 64 bf16 = 128B = 8 x 16B slots.
// Physical slot p of row r holds logical slot p ^ (r&7) (involution):
//  - staging fetches global slot (p ^ (r&7)) into linear LDS (gload_lds-safe)
//  - frag reads use phys = logical ^ (r&7) -> 8 distinct slots / 64 lanes
//    = structural LDS minimum, zero conflict penalty.
// ---------------------------------------------------------------------------

// Fused gate+up GEMM: BN=64 per matrix, dual accumulators share A tile.
// 4 waves 2m x 2n; wave = 64m x 32n per matrix (4x2 frags each).
template<int BF16W>
__global__ __launch_bounds__(256) void moe_gateup(
    const short* __restrict__ Asrc,
    const void* __restrict__ Wg_, const void* __restrict__ Wu_,
    short* __restrict__ Out,
    const int* __restrict__ counts, const int* __restrict__ slot_token,
    int Ndim, int Kdim, int expert_mode, int mtiles, int ntiles)
{
  int nwg = gridDim.x;
  int wg = ((blockIdx.x & 7) * (nwg >> 3)) + (blockIdx.x >> 3);  // XCD swizzle
  int m_t = wg % mtiles; wg /= mtiles;
  int n_t = wg % ntiles; int e = wg / ntiles;

  int cnt = T_TOK;
  size_t woff = 0;
  short* out = Out;
  if (expert_mode){
    cnt = counts[e]; if (cnt > CAPACITY) cnt = CAPACITY;
    if (m_t * 128 >= cnt) return;
    woff = (size_t)e * Ndim * Kdim;
    out = Out + (size_t)e * CAPACITY * Ndim;
  }
  const int m0 = m_t * 128, n0 = n_t * 64;

  __shared__ __align__(16) char smem[32768];
  char* sA  = smem;            // 128 x 64 bf16 = 16 KB
  char* sBg = smem + 16384;    //  64 x 64 = 8 KB
  char* sBu = smem + 24576;    //  64 x 64 = 8 KB

  const int tid = threadIdx.x;
  const int lane = tid & 63, wave = tid >> 6;
  const int wr = wave >> 1, wc = wave & 1;
  const int lrow = lane & 15, lk = lane >> 4;

  const int srow  = tid >> 3;            // staging row within 32-row group
  const int sxor  = srow & 7;
  const int pslot = tid & 7;
  const int lslot = pslot ^ sxor;        // logical slot fetched from global

  // A row source pointers (rows srow + 32*i), gathered in expert mode
  const short* aptr[4];
  #pragma unroll
  for (int i = 0; i < 4; ++i){
    int p = m0 + i * 32 + srow;
    const short* base;
    if (expert_mode){
      int q = (p < cnt) ? p : 0;
      base = Asrc + (size_t)slot_token[e * CAPACITY + q] * Kdim;
    } else {
      base = Asrc + (size_t)p * Kdim;
    }
    aptr[i] = base + (lslot << 3);
  }
  const short *bgp[2], *bup[2];
  const float *bgf[2], *buf2[2];
  #pragma unroll
  for (int i = 0; i < 2; ++i){
    size_t roff = (size_t)(n0 + i * 32 + srow) * Kdim + (lslot << 3);
    if (BF16W){
      bgp[i] = (const short*)Wg_ + woff + roff;
      bup[i] = (const short*)Wu_ + woff + roff;
    } else {
      bgf[i]  = (const float*)Wg_ + woff + roff;
      buf2[i] = (const float*)Wu_ + woff + roff;
    }
  }

  const floatx4 vzero = {0.f, 0.f, 0.f, 0.f};
  floatx4 accg[4][2], accu[4][2];
  #pragma unroll
  for (int i = 0; i < 4; ++i)
    #pragma unroll
    for (int j = 0; j < 2; ++j){ accg[i][j] = vzero; accu[i][j] = vzero; }

  const int fxor = lrow & 7;
  const int arowb = (wr * 64 + lrow) << 7;   // byte base of A frag rows
  const int browb = (wc * 32 + lrow) << 7;

  for (int k0 = 0; k0 < Kdim; k0 += 64){
    __syncthreads();
    if (BF16W){
      #pragma unroll
      for (int i = 0; i < 4; ++i) gl16(aptr[i] + k0, sA  + i * 4096 + tid * 16);
      #pragma unroll
      for (int i = 0; i < 2; ++i) gl16(bgp[i] + k0, sBg + i * 4096 + tid * 16);
      #pragma unroll
      for (int i = 0; i < 2; ++i) gl16(bup[i] + k0, sBu + i * 4096 + tid * 16);
    } else {
      #pragma unroll
      for (int i = 0; i < 4; ++i){
        short8 v = *(const short8*)(aptr[i] + k0);
        *(short8*)(sA + i * 4096 + tid * 16) = v;
      }
      #pragma unroll
      for (int i = 0; i < 2; ++i){
        float4 f0 = *(const float4*)(bgf[i] + k0);
        float4 f1 = *(const float4*)(bgf[i] + k0 + 4);
        short8 v = { f2b(f0.x), f2b(f0.y), f2b(f0.z), f2b(f0.w),
                     f2b(f1.x), f2b(f1.y), f2b(f1.z), f2b(f1.w) };
        *(short8*)(sBg + i * 4096 + tid * 16) = v;
        float4 g0 = *(const float4*)(buf2[i] + k0);
        float4 g1 = *(const float4*)(buf2[i] + k0 + 4);
        short8 w = { f2b(g0.x), f2b(g0.y), f2b(g0.z), f2b(g0.w),
                     f2b(g1.x), f2b(g1.y), f2b(g1.z), f2b(g1.w) };
        *(short8*)(sBu + i * 4096 + tid * 16) = w;
      }
    }
    __syncthreads();
    #pragma unroll
    for (int kh = 0; kh < 2; ++kh){
      const int soff = (((kh << 2) | lk) ^ fxor) << 4;
      short8 a[4], bg[2], bu[2];
      #pragma unroll
      for (int mf = 0; mf < 4; ++mf)
        a[mf] = *(const short8*)(sA + arowb + (mf << 11) + soff);
      #pragma unroll
      for (int nf = 0; nf < 2; ++nf){
        bg[nf] = *(const short8*)(sBg + browb + (nf << 11) + soff);
        bu[nf] = *(const short8*)(sBu + browb + (nf << 11) + soff);
      }
      #pragma unroll
      for (int mf = 0; mf < 4; ++mf)
        #pragma unroll
        for (int nf = 0; nf < 2; ++nf){
          accg[mf][nf] = __builtin_amdgcn_mfma_f32_16x16x32_bf16(a[mf], bg[nf], accg[mf][nf], 0, 0, 0);
          accu[mf][nf] = __builtin_amdgcn_mfma_f32_16x16x32_bf16(a[mf], bu[nf], accu[mf][nf], 0, 0, 0);
        }
    }
  }

  // epilogue: SiLU(g)*u -> bf16. C/D: col = lane&15, row = 4*(lane>>4)+r
  const int colbase = n0 + wc * 32 + lrow;
  #pragma unroll
  for (int mf = 0; mf < 4; ++mf){
    int pr = m0 + wr * 64 + mf * 16 + lk * 4;
    #pragma unroll
    for (int nf = 0; nf < 2; ++nf){
      floatx4 g4 = accg[mf][nf], u4 = accu[mf][nf];
      int col = colbase + nf * 16;
      #pragma unroll
      for (int r = 0; r < 4; ++r){
        float gv = g4[r], uv = u4[r];
        float a = (gv / (1.f + __expf(-gv))) * uv;
        out[(size_t)(pr + r) * Ndim + col] = f2b(a);
      }
    }
  }
}

// Down GEMM: BN=128; wave = 64x64 (4x4 frags). Expert mode scatters with
// atomicAdd weighted by routing prob; shared mode stores sigmoid_gate * C.
template<int BF16W>
__global__ __launch_bounds__(256) void moe_down(
    const short* __restrict__ Asrc,
    const void* __restrict__ Wd_,
    float* __restrict__ y,
    const int* __restrict__ counts, const int* __restrict__ slot_token,
    const float* __restrict__ slot_w, const float* __restrict__ sgate,
    int Kdim, int expert_mode, int mtiles, int ntiles)
{
  int nwg = gridDim.x;
  int wg = ((blockIdx.x & 7) * (nwg >> 3)) + (blockIdx.x >> 3);
  int m_t = wg % mtiles; wg /= mtiles;
  int n_t = wg % ntiles; int e = wg / ntiles;

  int cnt = T_TOK;
  const short* ab = Asrc;
  size_t woff = 0;
  if (expert_mode){
    cnt = counts[e]; if (cnt > CAPACITY) cnt = CAPACITY;
    if (m_t * 128 >= cnt) return;
    ab = Asrc + (size_t)e * CAPACITY * Kdim;
    woff = (size_t)e * HD * Kdim;
  }
  const int m0 = m_t * 128, n0 = n_t * 128;

  __shared__ __align__(16) char smem[32768];
  char* sA = smem;             // 128 x 64 = 16 KB
  char* sB = smem + 16384;     // 128 x 64 = 16 KB

  const int tid = threadIdx.x;
  const int lane = tid & 63, wave = tid >> 6;
  const int wr = wave >> 1, wc = wave & 1;
  const int lrow = lane & 15, lk = lane >> 4;

  const int srow  = tid >> 3;
  const int sxor  = srow & 7;
  const int pslot = tid & 7;
  const int lslot = pslot ^ sxor;

  const short* aptr[4];
  const short* bbp[4];
  const float* bbf[4];
  #pragma unroll
  for (int i = 0; i < 4; ++i){
    aptr[i] = ab + (size_t)(m0 + i * 32 + srow) * Kdim + (lslot << 3);
    size_t roff = (size_t)(n0 + i * 32 + srow) * Kdim + (lslot << 3);
    if (BF16W) bbp[i] = (const short*)Wd_ + woff + roff;
    else       bbf[i] = (const float*)Wd_ + woff + roff;
  }

  const floatx4 vzero = {0.f, 0.f, 0.f, 0.f};
  floatx4 acc[4][4];
  #pragma unroll
  for (int i = 0; i < 4; ++i)
    #pragma unroll
    for (int j = 0; j < 4; ++j) acc[i][j] = vzero;

  const int fxor = lrow & 7;
  const int arowb = (wr * 64 + lrow) << 7;
  const int browb = (wc * 64 + lrow) << 7;

  for (int k0 = 0; k0 < Kdim; k0 += 64){
    __syncthreads();
    #pragma unroll
    for (int i = 0; i < 4; ++i){
      if (BF16W){
        gl16(aptr[i] + k0, sA + i * 4096 + tid * 16);
        gl16(bbp[i] + k0, sB + i * 4096 + tid * 16);
      } else {
        short8 v = *(const short8*)(aptr[i] + k0);
        *(short8*)(sA + i * 4096 + tid * 16) = v;
        float4 f0 = *(const float4*)(bbf[i] + k0);
        float4 f1 = *(const float4*)(bbf[i] + k0 + 4);
        short8 w = { f2b(f0.x), f2b(f0.y), f2b(f0.z), f2b(f0.w),
                     f2b(f1.x), f2b(f1.y), f2b(f1.z), f2b(f1.w) };
        *(short8*)(sB + i * 4096 + tid * 16) = w;
      }
    }
    __syncthreads();
    #pragma unroll
    for (int kh = 0; kh < 2; ++kh){
      const int soff = (((kh << 2) | lk) ^ fxor) << 4;
      short8 a[4], b[4];
      #pragma unroll
      for (int mf = 0; mf < 4; ++mf)
        a[mf] = *(const short8*)(sA + arowb + (mf << 11) + soff);
      #pragma unroll
      for (int nf = 0; nf < 4; ++nf)
        b[nf] = *(const short8*)(sB + browb + (nf << 11) + soff);
      #pragma unroll
      for (int mf = 0; mf < 4; ++mf)
        #pragma unroll
        for (int nf = 0; nf < 4; ++nf)
          acc[mf][nf] = __builtin_amdgcn_mfma_f32_16x16x32_bf16(a[mf], b[nf], acc[mf][nf], 0, 0, 0);
    }
  }

  const int colb = n0 + wc * 64 + lrow;
  if (expert_mode){
    #pragma unroll
    for (int mf = 0; mf < 4; ++mf){
      int pr = m0 + wr * 64 + mf * 16 + lk * 4;
      #pragma unroll
      for (int r = 0; r < 4; ++r){
        int p = pr + r;
        if (p < cnt){
          int tok = slot_token[e * CAPACITY + p];
          float w = slot_w[e * CAPACITY + p];
          #pragma unroll
          for (int nf = 0; nf < 4; ++nf)
            atomicAdd(&y[(size_t)tok * HD + colb + nf * 16], w * acc[mf][nf][r]);
        }
      }
    }
  } else {
    #pragma unroll
    for (int mf = 0; mf < 4; ++mf){
      int pr = m0 + wr * 64 + mf * 16 + lk * 4;
      #pragma unroll
      for (int r = 0; r < 4; ++r){
        int t = pr + r;
        float sv = sgate[t];
        #pragma unroll
        for (int nf = 0; nf < 4; ++nf)
          y[(size_t)t * HD + colb + nf * 16] = sv * acc[mf][nf][r];
      }
    }
  }
}

extern "C" void kernel_launch(void* const* d_in, const int* in_sizes, int n_in,
                              void* d_out, int out_size, void* d_ws, size_t ws_size,
                              hipStream_t stream)
{
  (void)in_sizes; (void)n_in; (void)out_size;
  const float* x       = (const float*)d_in[0];
  const float* gate_w  = (const float*)d_in[1];
  const float* we_gate = (const float*)d_in[2];
  const float* we_up   = (const float*)d_in[3];
  const float* we_down = (const float*)d_in[4];
  const float* wsg     = (const float*)d_in[5];
  const float* wsu     = (const float*)d_in[6];
  const float* wsd     = (const float*)d_in[7];
  const float* sg_w    = (const float*)d_in[8];

  float* y      = (float*)d_out;                 // [T, H]
  float* logits = y + (size_t)T_TOK * HD;        // [T, E]

  const size_t SZ_XB  = (size_t)T_TOK * HD * 2;        // 8,388,608
  const size_t SZ_WE  = (size_t)NE * ID * HD * 2;      // 92,274,688
  const size_t SZ_WS  = (size_t)SID * HD * 2;          // 23,068,672
  const size_t SZ_ACT = (size_t)NE * CAPACITY * ID * 2;// 46,137,344
  const size_t SZ_ACS = (size_t)T_TOK * SID * 2;       // 23,068,672

  char* ws = (char*)d_ws;

  // big layout (pre-converted bf16 weights)
  size_t off = 0;
  short* xb   = (short*)(ws + off); off += SZ_XB;
  short* wbeg = (short*)(ws + off); off += SZ_WE;
  short* wbeu = (short*)(ws + off); off += SZ_WE;
  short* wbed = (short*)(ws + off); off += SZ_WE;
  short* wbsg = (short*)(ws + off); off += SZ_WS;
  short* wbsu = (short*)(ws + off); off += SZ_WS;
  short* wbsd = (short*)(ws + off); off += SZ_WS;
  short* act  = (short*)(ws + off); off += SZ_ACT;
  short* acts = (short*)(ws + off); off += SZ_ACS;
  int*   slot_token = (int*)  (ws + off); off += 65536;
  float* slot_w     = (float*)(ws + off); off += 65536;
  int*   counts     = (int*)  (ws + off); off += 256;
  float* sg         = (float*)(ws + off); off += 8192;
  const size_t WS_NEED = off;

  if (ws_size >= WS_NEED){
    moe_zero<<<1, 64, 0, stream>>>(counts);
    moe_convert<<<2048, 256, 0, stream>>>(we_gate, wbeg, NE * ID * HD / 8);
    moe_convert<<<2048, 256, 0, stream>>>(we_up,   wbeu, NE * ID * HD / 8);
    moe_convert<<<2048, 256, 0, stream>>>(we_down, wbed, NE * ID * HD / 8);
    moe_convert<<<2048, 256, 0, stream>>>(wsg, wbsg, SID * HD / 8);
    moe_convert<<<2048, 256, 0, stream>>>(wsu, wbsu, SID * HD / 8);
    moe_convert<<<2048, 256, 0, stream>>>(wsd, wbsd, SID * HD / 8);
    moe_router<<<512, 256, 0, stream>>>(x, gate_w, sg_w, logits, xb,
                                        counts, slot_token, slot_w, sg);
    moe_gateup<1><<<16 * 88, 256, 0, stream>>>(xb, wbsg, wbsu, acts,
                                               nullptr, nullptr, SID, HD, 0, 16, 88);
    moe_gateup<1><<<8 * 22 * NE, 256, 0, stream>>>(xb, wbeg, wbeu, act,
                                                   counts, slot_token, ID, HD, 1, 8, 22);
    moe_down<1><<<16 * 16, 256, 0, stream>>>(acts, wbsd, y, nullptr, nullptr,
                                             nullptr, sg, SID, 0, 16, 16);
    moe_down<1><<<8 * 16 * NE, 256, 0, stream>>>(act, wbed, y, counts, slot_token,
                                                 slot_w, nullptr, ID, 1, 8, 16);
  } else {
    // fallback: fp32 weights, in-loop conversion (compact ws layout)
    size_t o2 = 0;
    short* xb2   = (short*)(ws + o2); o2 += SZ_XB;
    short* act2  = (short*)(ws + o2); o2 += SZ_ACT;
    short* acts2 = (short*)(ws + o2); o2 += SZ_ACS;
    int*   st2 = (int*)  (ws + o2); o2 += 65536;
    float* sw2 = (float*)(ws + o2); o2 += 65536;
    int*   cn2 = (int*)  (ws + o2); o2 += 256;
    float* sg2 = (float*)(ws + o2);
    moe_zero<<<1, 64, 0, stream>>>(cn2);
    moe_router<<<512, 256, 0, stream>>>(x, gate_w, sg_w, logits, xb2,
                                        cn2, st2, sw2, sg2);
    moe_gateup<0><<<16 * 88, 256, 0, stream>>>(xb2, wsg, wsu, acts2,
                                               nullptr, nullptr, SID, HD, 0, 16, 88);
    moe_gateup<0><<<8 * 22 * NE, 256, 0, stream>>>(xb2, we_gate, we_up, act2,
                                                   cn2, st2, ID, HD, 1, 8, 22);
    moe_down<0><<<16 * 16, 256, 0, stream>>>(acts2, wsd, y, nullptr, nullptr,
                                             nullptr, sg2, SID, 0, 16, 16);
    moe_down<0><<<8 * 16 * NE, 256, 0, stream>>>(act2, we_down, y, cn2, st2,
                                                 sw2, nullptr, ID, 1, 8, 16);
  }
}

// Round 3
// 841.615 us; speedup vs baseline: 1.3948x; 1.0852x over previous
//
#include <hip/hip_runtime.h>

#define T_TOK 2048
#define NE 16
#define KTOP 4
#define HD 2048
#define ID 1408
#define SID 5632
#define CAPACITY 1024

typedef __attribute__((ext_vector_type(8))) short short8;   // 8 x bf16
typedef __attribute__((ext_vector_type(4))) float floatx4;  // MFMA acc

// fp32 -> bf16 round-to-nearest-even
__device__ __forceinline__ short f2b(float f){
  union { float f; unsigned u; } v; v.f = f;
  unsigned r = v.u + 0x7fffu + ((v.u >> 16) & 1u);
  return (short)(r >> 16);
}
__device__ __forceinline__ float b2f(short s){
  union { float f; unsigned u; } v; v.u = ((unsigned)(unsigned short)s) << 16;
  return v.f;
}
// async global->LDS, 16B per lane (wave-uniform LDS base + lane*16)
__device__ __forceinline__ void gl16(const void* g, void* l){
  __builtin_amdgcn_global_load_lds(
      (const __attribute__((address_space(1))) void*)g,
      (__attribute__((address_space(3))) void*)l, 16, 0, 0);
}

__global__ void moe_zero(int* __restrict__ counts){
  if (threadIdx.x < NE) counts[threadIdx.x] = 0;
}

// All six weight tensors fp32 -> bf16 in one grid-stride kernel.
// dst is one contiguous region: [eg | eu | ed | sg | su | sd].
__global__ void moe_convert_all(const float* __restrict__ eg, const float* __restrict__ eu,
                                const float* __restrict__ ed, const float* __restrict__ sgp,
                                const float* __restrict__ sup, const float* __restrict__ sdp,
                                short* __restrict__ dst)
{
  const long long EW = (long long)NE * ID * HD / 8;   // 5,767,168
  const long long SW = (long long)SID * HD / 8;       // 1,441,792
  const long long total = 3 * EW + 3 * SW;
  long long stride = (long long)gridDim.x * blockDim.x;
  for (long long i = (long long)blockIdx.x * blockDim.x + threadIdx.x; i < total; i += stride){
    const float* s; long long j;
    if (i < 2 * EW){
      if (i < EW){ s = eg; j = i; } else { s = eu; j = i - EW; }
    } else if (i < 3 * EW){ s = ed; j = i - 2 * EW; }
    else if (i < 3 * EW + SW){ s = sgp; j = i - 3 * EW; }
    else if (i < 3 * EW + 2 * SW){ s = sup; j = i - 3 * EW - SW; }
    else { s = sdp; j = i - 3 * EW - 2 * SW; }
    float4 f0 = ((const float4*)s)[j * 2];
    float4 f1 = ((const float4*)s)[j * 2 + 1];
    short8 v = { f2b(f0.x), f2b(f0.y), f2b(f0.z), f2b(f0.w),
                 f2b(f1.x), f2b(f1.y), f2b(f1.z), f2b(f1.w) };
    ((short8*)dst)[i] = v;
  }
}

// Router: fp32 logits -> d_out tail; softmax+top4; slot assignment via atomics
// (order-free: CAP = 2x mean load, drop prob ~0); x -> bf16; shared-gate sigmoid.
// Also records per-token slot ids + weights for the gather-combine.
__global__ void moe_router(const float* __restrict__ x,
                           const float* __restrict__ gate_w,
                           const float* __restrict__ sg_w,
                           float* __restrict__ logits_out,
                           short* __restrict__ xb,
                           int* __restrict__ counts,
                           int* __restrict__ slot_token,
                           float* __restrict__ slot_w,
                           int* __restrict__ tslot,
                           float* __restrict__ tw,
                           float* __restrict__ sg)
{
  int wave = threadIdx.x >> 6, lane = threadIdx.x & 63;
  int t = (blockIdx.x << 2) + wave;
  if (t >= T_TOK) return;
  const float4* xr = (const float4*)(x + (size_t)t * HD);
  short8* xbw = (short8*)(xb + (size_t)t * HD);
  float acc[17];
  #pragma unroll
  for (int e = 0; e < 17; ++e) acc[e] = 0.f;
  #pragma unroll
  for (int j = 0; j < 4; ++j){
    int i4 = (j * 64 + lane) * 2;
    float4 x0 = xr[i4], x1 = xr[i4 + 1];
    short8 v = { f2b(x0.x), f2b(x0.y), f2b(x0.z), f2b(x0.w),
                 f2b(x1.x), f2b(x1.y), f2b(x1.z), f2b(x1.w) };
    xbw[j * 64 + lane] = v;
    #pragma unroll
    for (int e = 0; e < 16; ++e){
      const float4* gr = (const float4*)(gate_w + e * HD);
      float4 g0 = gr[i4], g1 = gr[i4 + 1];
      acc[e] += x0.x*g0.x + x0.y*g0.y + x0.z*g0.z + x0.w*g0.w
              + x1.x*g1.x + x1.y*g1.y + x1.z*g1.z + x1.w*g1.w;
    }
    const float4* sr = (const float4*)sg_w;
    float4 s0 = sr[i4], s1 = sr[i4 + 1];
    acc[16] += x0.x*s0.x + x0.y*s0.y + x0.z*s0.z + x0.w*s0.w
             + x1.x*s1.x + x1.y*s1.y + x1.z*s1.z + x1.w*s1.w;
  }
  #pragma unroll
  for (int e = 0; e < 17; ++e){
    float v = acc[e];
    #pragma unroll
    for (int off = 32; off > 0; off >>= 1) v += __shfl_xor(v, off, 64);
    acc[e] = v;
  }
  if (lane == 0){
    float m = acc[0];
    #pragma unroll
    for (int e = 1; e < 16; ++e) m = fmaxf(m, acc[e]);
    float p[16]; float s = 0.f;
    #pragma unroll
    for (int e = 0; e < 16; ++e){ p[e] = expf(acc[e] - m); s += p[e]; }
    float inv = 1.f / s;
    #pragma unroll
    for (int e = 0; e < 16; ++e) logits_out[t * 16 + e] = acc[e];
    unsigned used = 0;
    for (int k = 0; k < KTOP; ++k){
      float best = -1.f; int bi = 0;
      #pragma unroll
      for (int e = 0; e < 16; ++e){
        float pe = ((used >> e) & 1u) ? -1.f : p[e];
        if (pe > best){ best = pe; bi = e; }
      }
      used |= (1u << bi);
      int pos = atomicAdd(&counts[bi], 1);
      int enc = -1;
      if (pos < CAPACITY){
        slot_token[bi * CAPACITY + pos] = t;
        slot_w[bi * CAPACITY + pos] = best * inv;
        enc = bi * CAPACITY + pos;
      }
      tslot[t * KTOP + k] = enc;
      tw[t * KTOP + k] = best * inv;
    }
    sg[t] = 1.f / (1.f + expf(-acc[16]));
  }
}

// ---------------------------------------------------------------------------
// GEMM tiles: BM=128, BK=64. LDS rows: 64 bf16 = 128B = 8 x 16B slots.
// Physical slot p of row r holds logical slot p ^ (r&7) (involution):
// staging fetches pre-swizzled global addresses into linear LDS
// (global_load_lds-safe); frag reads XOR back -> 2-way bank aliasing (free).
// BF16W=1: double-buffered LDS, stage(next) issued BEFORE compute(cur),
// ONE barrier per K-step (its vmcnt/lgkm drain is the phase boundary).
// ---------------------------------------------------------------------------

// Fused gate+up GEMM: BN=64 per matrix, dual accumulators share the A tile.
template<int BF16W>
__global__ __launch_bounds__(256) void moe_gateup(
    const short* __restrict__ Asrc,
    const void* __restrict__ Wg_, const void* __restrict__ Wu_,
    short* __restrict__ Out,
    const int* __restrict__ counts, const int* __restrict__ slot_token,
    int Ndim, int Kdim, int expert_mode, int mtiles, int ntiles)
{
  int nwg = gridDim.x;
  int wg = ((blockIdx.x & 7) * (nwg >> 3)) + (blockIdx.x >> 3);  // XCD swizzle
  int m_t = wg % mtiles; wg /= mtiles;
  int n_t = wg % ntiles; int e = wg / ntiles;

  int cnt = T_TOK; size_t woff = 0; short* out = Out;
  if (expert_mode){
    cnt = counts[e]; if (cnt > CAPACITY) cnt = CAPACITY;
    if (m_t * 128 >= cnt) return;
    woff = (size_t)e * Ndim * Kdim;
    out = Out + (size_t)e * CAPACITY * Ndim;
  }
  const int m0 = m_t * 128, n0 = n_t * 64;

  __shared__ __align__(16) char smem[2][32768];  // per buf: A 16K | Bg 8K | Bu 8K

  const int tid = threadIdx.x;
  const int lane = tid & 63, wave = tid >> 6;
  const int wr = wave >> 1, wc = wave & 1;
  const int lrow = lane & 15, lk = lane >> 4;

  const int srow = tid >> 3, pslot = tid & 7;
  const int lslot = pslot ^ (srow & 7);

  const short* aptr[4];
  #pragma unroll
  for (int i = 0; i < 4; ++i){
    int p = m0 + i * 32 + srow;
    const short* base;
    if (expert_mode){
      int q = (p < cnt) ? p : 0;
      base = Asrc + (size_t)slot_token[e * CAPACITY + q] * Kdim;
    } else base = Asrc + (size_t)p * Kdim;
    aptr[i] = base + (lslot << 3);
  }
  const short *bgp[2], *bup[2];
  const float *bgf[2], *buf2[2];
  #pragma unroll
  for (int i = 0; i < 2; ++i){
    size_t roff = (size_t)(n0 + i * 32 + srow) * Kdim + (lslot << 3);
    if (BF16W){
      bgp[i] = (const short*)Wg_ + woff + roff;
      bup[i] = (const short*)Wu_ + woff + roff;
    } else {
      bgf[i]  = (const float*)Wg_ + woff + roff;
      buf2[i] = (const float*)Wu_ + woff + roff;
    }
  }

  const floatx4 vzero = {0.f, 0.f, 0.f, 0.f};
  floatx4 accg[4][2], accu[4][2];
  #pragma unroll
  for (int i = 0; i < 4; ++i)
    #pragma unroll
    for (int j = 0; j < 2; ++j){ accg[i][j] = vzero; accu[i][j] = vzero; }

  const int fxor = lrow & 7;
  const int arowb = (wr * 64 + lrow) << 7;
  const int browb = (wc * 32 + lrow) << 7;

  if (BF16W){
    // --- pipelined: one barrier per K-step ---
    {
      char* b = smem[0];
      #pragma unroll
      for (int i = 0; i < 4; ++i) gl16(aptr[i], b + i * 4096 + tid * 16);
      #pragma unroll
      for (int i = 0; i < 2; ++i) gl16(bgp[i], b + 16384 + i * 4096 + tid * 16);
      #pragma unroll
      for (int i = 0; i < 2; ++i) gl16(bup[i], b + 24576 + i * 4096 + tid * 16);
    }
    __syncthreads();
    int cur = 0;
    for (int k0 = 0; k0 < Kdim; k0 += 64){
      if (k0 + 64 < Kdim){
        char* b = smem[cur ^ 1];
        #pragma unroll
        for (int i = 0; i < 4; ++i) gl16(aptr[i] + k0 + 64, b + i * 4096 + tid * 16);
        #pragma unroll
        for (int i = 0; i < 2; ++i) gl16(bgp[i] + k0 + 64, b + 16384 + i * 4096 + tid * 16);
        #pragma unroll
        for (int i = 0; i < 2; ++i) gl16(bup[i] + k0 + 64, b + 24576 + i * 4096 + tid * 16);
      }
      const char* bb = smem[cur];
      #pragma unroll
      for (int kh = 0; kh < 2; ++kh){
        const int soff = (((kh << 2) | lk) ^ fxor) << 4;
        short8 a[4], bg[2], bu[2];
        #pragma unroll
        for (int mf = 0; mf < 4; ++mf)
          a[mf] = *(const short8*)(bb + arowb + (mf << 11) + soff);
        #pragma unroll
        for (int nf = 0; nf < 2; ++nf){
          bg[nf] = *(const short8*)(bb + 16384 + browb + (nf << 11) + soff);
          bu[nf] = *(const short8*)(bb + 24576 + browb + (nf << 11) + soff);
        }
        #pragma unroll
        for (int mf = 0; mf < 4; ++mf)
          #pragma unroll
          for (int nf = 0; nf < 2; ++nf){
            accg[mf][nf] = __builtin_amdgcn_mfma_f32_16x16x32_bf16(a[mf], bg[nf], accg[mf][nf], 0, 0, 0);
            accu[mf][nf] = __builtin_amdgcn_mfma_f32_16x16x32_bf16(a[mf], bu[nf], accu[mf][nf], 0, 0, 0);
          }
      }
      __syncthreads();
      cur ^= 1;
    }
  } else {
    // --- fallback: fp32 weights, reg-staged, serial 2-barrier ---
    char* sA = smem[0]; char* sBg = sA + 16384; char* sBu = sA + 24576;
    for (int k0 = 0; k0 < Kdim; k0 += 64){
      __syncthreads();
      #pragma unroll
      for (int i = 0; i < 4; ++i){
        short8 v = *(const short8*)(aptr[i] + k0);
        *(short8*)(sA + i * 4096 + tid * 16) = v;
      }
      #pragma unroll
      for (int i = 0; i < 2; ++i){
        float4 f0 = *(const float4*)(bgf[i] + k0);
        float4 f1 = *(const float4*)(bgf[i] + k0 + 4);
        short8 v = { f2b(f0.x), f2b(f0.y), f2b(f0.z), f2b(f0.w),
                     f2b(f1.x), f2b(f1.y), f2b(f1.z), f2b(f1.w) };
        *(short8*)(sBg + i * 4096 + tid * 16) = v;
        float4 g0 = *(const float4*)(buf2[i] + k0);
        float4 g1 = *(const float4*)(buf2[i] + k0 + 4);
        short8 w = { f2b(g0.x), f2b(g0.y), f2b(g0.z), f2b(g0.w),
                     f2b(g1.x), f2b(g1.y), f2b(g1.z), f2b(g1.w) };
        *(short8*)(sBu + i * 4096 + tid * 16) = w;
      }
      __syncthreads();
      #pragma unroll
      for (int kh = 0; kh < 2; ++kh){
        const int soff = (((kh << 2) | lk) ^ fxor) << 4;
        short8 a[4], bg[2], bu[2];
        #pragma unroll
        for (int mf = 0; mf < 4; ++mf)
          a[mf] = *(const short8*)(sA + arowb + (mf << 11) + soff);
        #pragma unroll
        for (int nf = 0; nf < 2; ++nf){
          bg[nf] = *(const short8*)(sBg + browb + (nf << 11) + soff);
          bu[nf] = *(const short8*)(sBu + browb + (nf << 11) + soff);
        }
        #pragma unroll
        for (int mf = 0; mf < 4; ++mf)
          #pragma unroll
          for (int nf = 0; nf < 2; ++nf){
            accg[mf][nf] = __builtin_amdgcn_mfma_f32_16x16x32_bf16(a[mf], bg[nf], accg[mf][nf], 0, 0, 0);
            accu[mf][nf] = __builtin_amdgcn_mfma_f32_16x16x32_bf16(a[mf], bu[nf], accu[mf][nf], 0, 0, 0);
          }
      }
    }
  }

  // epilogue: SiLU(g)*u -> bf16. C/D: col = lane&15, row = 4*(lane>>4)+r
  const int colbase = n0 + wc * 32 + lrow;
  #pragma unroll
  for (int mf = 0; mf < 4; ++mf){
    int pr = m0 + wr * 64 + mf * 16 + lk * 4;
    #pragma unroll
    for (int nf = 0; nf < 2; ++nf){
      floatx4 g4 = accg[mf][nf], u4 = accu[mf][nf];
      int col = colbase + nf * 16;
      #pragma unroll
      for (int r = 0; r < 4; ++r){
        float gv = g4[r], uv = u4[r];
        float a = (gv / (1.f + __expf(-gv))) * uv;
        out[(size_t)(pr + r) * Ndim + col] = f2b(a);
      }
    }
  }
}

// Down GEMM. BN = NF*32 (NF=2 shared, NF=4 expert). Wave = 64 x (NF*16).
// expert: plain bf16 stores to eo (combine gathers later); atomic fallback if !eo.
// shared: y = sigmoid_gate * C (plain f32 stores, initializes y).
template<int BF16W, int NF>
__global__ __launch_bounds__(256) void moe_down(
    const short* __restrict__ Asrc, const void* __restrict__ Wd_,
    float* __restrict__ y, short* __restrict__ eo,
    const int* __restrict__ counts, const int* __restrict__ slot_token,
    const float* __restrict__ slot_w, const float* __restrict__ sgate,
    int Kdim, int expert_mode, int mtiles, int ntiles)
{
  constexpr int BN = NF * 32;
  int nwg = gridDim.x;
  int wg = ((blockIdx.x & 7) * (nwg >> 3)) + (blockIdx.x >> 3);
  int m_t = wg % mtiles; wg /= mtiles;
  int n_t = wg % ntiles; int e = wg / ntiles;

  int cnt = T_TOK; const short* ab = Asrc; size_t woff = 0;
  if (expert_mode){
    cnt = counts[e]; if (cnt > CAPACITY) cnt = CAPACITY;
    if (m_t * 128 >= cnt) return;
    ab = Asrc + (size_t)e * CAPACITY * Kdim;
    woff = (size_t)e * HD * Kdim;
  }
  const int m0 = m_t * 128, n0 = n_t * BN;

  __shared__ __align__(16) char smem[2][16384 + NF * 4096];

  const int tid = threadIdx.x;
  const int lane = tid & 63, wave = tid >> 6;
  const int wr = wave >> 1, wc = wave & 1;
  const int lrow = lane & 15, lk = lane >> 4;

  const int srow = tid >> 3, pslot = tid & 7;
  const int lslot = pslot ^ (srow & 7);

  const short* aptr[4];
  #pragma unroll
  for (int i = 0; i < 4; ++i)
    aptr[i] = ab + (size_t)(m0 + i * 32 + srow) * Kdim + (lslot << 3);
  const short* bbp[NF];
  const float* bbf[NF];
  #pragma unroll
  for (int i = 0; i < NF; ++i){
    size_t roff = (size_t)(n0 + i * 32 + srow) * Kdim + (lslot << 3);
    if (BF16W) bbp[i] = (const short*)Wd_ + woff + roff;
    else       bbf[i] = (const float*)Wd_ + woff + roff;
  }

  const floatx4 vzero = {0.f, 0.f, 0.f, 0.f};
  floatx4 acc[4][NF];
  #pragma unroll
  for (int i = 0; i < 4; ++i)
    #pragma unroll
    for (int j = 0; j < NF; ++j) acc[i][j] = vzero;

  const int fxor = lrow & 7;
  const int arowb = (wr * 64 + lrow) << 7;
  const int browb = (wc * (NF * 16) + lrow) << 7;

  if (BF16W){
    {
      char* b = smem[0];
      #pragma unroll
      for (int i = 0; i < 4; ++i) gl16(aptr[i], b + i * 4096 + tid * 16);
      #pragma unroll
      for (int i = 0; i < NF; ++i) gl16(bbp[i], b + 16384 + i * 4096 + tid * 16);
    }
    __syncthreads();
    int cur = 0;
    for (int k0 = 0; k0 < Kdim; k0 += 64){
      if (k0 + 64 < Kdim){
        char* b = smem[cur ^ 1];
        #pragma unroll
        for (int i = 0; i < 4; ++i) gl16(aptr[i] + k0 + 64, b + i * 4096 + tid * 16);
        #pragma unroll
        for (int i = 0; i < NF; ++i) gl16(bbp[i] + k0 + 64, b + 16384 + i * 4096 + tid * 16);
      }
      const char* bb = smem[cur];
      #pragma unroll
      for (int kh = 0; kh < 2; ++kh){
        const int soff = (((kh << 2) | lk) ^ fxor) << 4;
        short8 a[4], b[NF];
        #pragma unroll
        for (int mf = 0; mf < 4; ++mf)
          a[mf] = *(const short8*)(bb + arowb + (mf << 11) + soff);
        #pragma unroll
        for (int nf = 0; nf < NF; ++nf)
          b[nf] = *(const short8*)(bb + 16384 + browb + (nf << 11) + soff);
        #pragma unroll
        for (int mf = 0; mf < 4; ++mf)
          #pragma unroll
          for (int nf = 0; nf < NF; ++nf)
            acc[mf][nf] = __builtin_amdgcn_mfma_f32_16x16x32_bf16(a[mf], b[nf], acc[mf][nf], 0, 0, 0);
      }
      __syncthreads();
      cur ^= 1;
    }
  } else {
    char* sA = smem[0]; char* sB = sA + 16384;
    for (int k0 = 0; k0 < Kdim; k0 += 64){
      __syncthreads();
      #pragma unroll
      for (int i = 0; i < 4; ++i){
        short8 v = *(const short8*)(aptr[i] + k0);
        *(short8*)(sA + i * 4096 + tid * 16) = v;
      }
      #pragma unroll
      for (int i = 0; i < NF; ++i){
        float4 f0 = *(const float4*)(bbf[i] + k0);
        float4 f1 = *(const float4*)(bbf[i] + k0 + 4);
        short8 w = { f2b(f0.x), f2b(f0.y), f2b(f0.z), f2b(f0.w),
                     f2b(f1.x), f2b(f1.y), f2b(f1.z), f2b(f1.w) };
        *(short8*)(sB + i * 4096 + tid * 16) = w;
      }
      __syncthreads();
      #pragma unroll
      for (int kh = 0; kh < 2; ++kh){
        const int soff = (((kh << 2) | lk) ^ fxor) << 4;
        short8 a[4], b[NF];
        #pragma unroll
        for (int mf = 0; mf < 4; ++mf)
          a[mf] = *(const short8*)(sA + arowb + (mf << 11) + soff);
        #pragma unroll
        for (int nf = 0; nf < NF; ++nf)
          b[nf] = *(const short8*)(sB + browb + (nf << 11) + soff);
        #pragma unroll
        for (int mf = 0; mf < 4; ++mf)
          #pragma unroll
          for (int nf = 0; nf < NF; ++nf)
            acc[mf][nf] = __builtin_amdgcn_mfma_f32_16x16x32_bf16(a[mf], b[nf], acc[mf][nf], 0, 0, 0);
      }
    }
  }

  const int colb = n0 + wc * (NF * 16) + lrow;
  if (expert_mode){
    if (eo){
      #pragma unroll
      for (int mf = 0; mf < 4; ++mf){
        int pr = m0 + wr * 64 + mf * 16 + lk * 4;
        #pragma unroll
        for (int r = 0; r < 4; ++r){
          int p = pr + r;  // < CAPACITY by construction
          #pragma unroll
          for (int nf = 0; nf < NF; ++nf)
            eo[(size_t)(e * CAPACITY + p) * HD + colb + nf * 16] = f2b(acc[mf][nf][r]);
        }
      }
    } else {
      #pragma unroll
      for (int mf = 0; mf < 4; ++mf){
        int pr = m0 + wr * 64 + mf * 16 + lk * 4;
        #pragma unroll
        for (int r = 0; r < 4; ++r){
          int p = pr + r;
          if (p < cnt){
            int tok = slot_token[e * CAPACITY + p];
            float w = slot_w[e * CAPACITY + p];
            #pragma unroll
            for (int nf = 0; nf < NF; ++nf)
              atomicAdd(&y[(size_t)tok * HD + colb + nf * 16], w * acc[mf][nf][r]);
          }
        }
      }
    }
  } else {
    #pragma unroll
    for (int mf = 0; mf < 4; ++mf){
      int pr = m0 + wr * 64 + mf * 16 + lk * 4;
      #pragma unroll
      for (int r = 0; r < 4; ++r){
        int t = pr + r;
        float sv = sgate[t];
        #pragma unroll
        for (int nf = 0; nf < NF; ++nf)
          y[(size_t)t * HD + colb + nf * 16] = sv * acc[mf][nf][r];
      }
    }
  }
}

// Gather-combine: y[t] += sum_k w_k * eo[slot_k]  (no atomics)
__global__ void moe_combine(const short* __restrict__ eo,
                            const int* __restrict__ tslot,
                            const float* __restrict__ tw,
                            float* __restrict__ y)
{
  int t = blockIdx.x;
  int o = threadIdx.x << 3;
  float* yp = y + (size_t)t * HD + o;
  float4 a0 = *(const float4*)yp, a1 = *(const float4*)(yp + 4);
  float acc[8] = {a0.x, a0.y, a0.z, a0.w, a1.x, a1.y, a1.z, a1.w};
  #pragma unroll
  for (int k = 0; k < KTOP; ++k){
    int s = tslot[t * KTOP + k];
    if (s >= 0){
      float w = tw[t * KTOP + k];
      short8 v = *(const short8*)(eo + (size_t)s * HD + o);
      #pragma unroll
      for (int j = 0; j < 8; ++j) acc[j] += w * b2f(v[j]);
    }
  }
  float4 r0 = {acc[0], acc[1], acc[2], acc[3]};
  float4 r1 = {acc[4], acc[5], acc[6], acc[7]};
  *(float4*)yp = r0; *(float4*)(yp + 4) = r1;
}

extern "C" void kernel_launch(void* const* d_in, const int* in_sizes, int n_in,
                              void* d_out, int out_size, void* d_ws, size_t ws_size,
                              hipStream_t stream)
{
  (void)in_sizes; (void)n_in; (void)out_size;
  const float* x       = (const float*)d_in[0];
  const float* gate_w  = (const float*)d_in[1];
  const float* we_gate = (const float*)d_in[2];
  const float* we_up   = (const float*)d_in[3];
  const float* we_down = (const float*)d_in[4];
  const float* wsg     = (const float*)d_in[5];
  const float* wsu     = (const float*)d_in[6];
  const float* wsd     = (const float*)d_in[7];
  const float* sg_w    = (const float*)d_in[8];

  float* y      = (float*)d_out;                 // [T, H]
  float* logits = y + (size_t)T_TOK * HD;        // [T, E]

  const size_t SZ_XB  = (size_t)T_TOK * HD * 2;
  const size_t SZ_WE  = (size_t)NE * ID * HD * 2;
  const size_t SZ_WS  = (size_t)SID * HD * 2;
  const size_t SZ_ACT = (size_t)NE * CAPACITY * ID * 2;
  const size_t SZ_ACS = (size_t)T_TOK * SID * 2;
  const size_t SZ_EO  = (size_t)NE * CAPACITY * HD * 2;
  const size_t SZ_SMALL = 65536 + 65536 + 32768 + 32768 + 256 + 8192;

  const size_t NEED_B = SZ_XB + 3 * SZ_WE + 3 * SZ_WS + SZ_ACT + SZ_ACS + SZ_SMALL;
  const size_t NEED_A = NEED_B + SZ_EO;

  char* ws = (char*)d_ws;
  size_t off = 0;
  short* xb   = (short*)(ws + off); off += SZ_XB;
  short* wbeg = (short*)(ws + off); off += SZ_WE;
  short* wbeu = (short*)(ws + off); off += SZ_WE;
  short* wbed = (short*)(ws + off); off += SZ_WE;
  short* wbsg = (short*)(ws + off); off += SZ_WS;
  short* wbsu = (short*)(ws + off); off += SZ_WS;
  short* wbsd = (short*)(ws + off); off += SZ_WS;
  short* act  = (short*)(ws + off); off += SZ_ACT;
  short* acts = (short*)(ws + off); off += SZ_ACS;
  short* eo   = (short*)(ws + off);
  if (ws_size >= NEED_A) off += SZ_EO; else eo = nullptr;
  int*   slot_token = (int*)  (ws + off); off += 65536;
  float* slot_w     = (float*)(ws + off); off += 65536;
  int*   tslot      = (int*)  (ws + off); off += 32768;
  float* tw         = (float*)(ws + off); off += 32768;
  int*   counts     = (int*)  (ws + off); off += 256;
  float* sg         = (float*)(ws + off);

  if (ws_size >= NEED_B){
    moe_zero<<<1, 64, 0, stream>>>(counts);
    moe_convert_all<<<2048, 256, 0, stream>>>(we_gate, we_up, we_down, wsg, wsu, wsd, wbeg);
    moe_router<<<512, 256, 0, stream>>>(x, gate_w, sg_w, logits, xb,
                                        counts, slot_token, slot_w, tslot, tw, sg);
    moe_gateup<1><<<16 * 88, 256, 0, stream>>>(xb, wbsg, wbsu, acts,
                                               nullptr, nullptr, SID, HD, 0, 16, 88);
    moe_gateup<1><<<8 * 22 * NE, 256, 0, stream>>>(xb, wbeg, wbeu, act,
                                                   counts, slot_token, ID, HD, 1, 8, 22);
    moe_down<1, 2><<<16 * 32, 256, 0, stream>>>(acts, wbsd, y, nullptr, nullptr, nullptr,
                                                nullptr, sg, SID, 0, 16, 32);
    moe_down<1, 4><<<8 * 16 * NE, 256, 0, stream>>>(act, wbed, y, eo, counts, slot_token,
                                                    slot_w, nullptr, ID, 1, 8, 16);
    if (eo) moe_combine<<<T_TOK, 256, 0, stream>>>(eo, tslot, tw, y);
  } else {
    // compact fp32 fallback: reg-staged serial GEMMs + atomic combine
    size_t o2 = 0;
    short* xb2   = (short*)(ws + o2); o2 += SZ_XB;
    short* act2  = (short*)(ws + o2); o2 += SZ_ACT;
    short* acts2 = (short*)(ws + o2); o2 += SZ_ACS;
    int*   st2 = (int*)  (ws + o2); o2 += 65536;
    float* sw2 = (float*)(ws + o2); o2 += 65536;
    int*   ts2 = (int*)  (ws + o2); o2 += 32768;
    float* tw2 = (float*)(ws + o2); o2 += 32768;
    int*   cn2 = (int*)  (ws + o2); o2 += 256;
    float* sg2 = (float*)(ws + o2);
    moe_zero<<<1, 64, 0, stream>>>(cn2);
    moe_router<<<512, 256, 0, stream>>>(x, gate_w, sg_w, logits, xb2,
                                        cn2, st2, sw2, ts2, tw2, sg2);
    moe_gateup<0><<<16 * 88, 256, 0, stream>>>(xb2, wsg, wsu, acts2,
                                               nullptr, nullptr, SID, HD, 0, 16, 88);
    moe_gateup<0><<<8 * 22 * NE, 256, 0, stream>>>(xb2, we_gate, we_up, act2,
                                                   cn2, st2, ID, HD, 1, 8, 22);
    moe_down<0, 2><<<16 * 32, 256, 0, stream>>>(acts2, wsd, y, nullptr, nullptr, nullptr,
                                                nullptr, sg2, SID, 0, 16, 32);
    moe_down<0, 4><<<8 * 16 * NE, 256, 0, stream>>>(act2, we_down, y, nullptr, cn2, st2,
                                                    sw2, nullptr, ID, 1, 8, 16);
  }
}

// Round 4
// 800.402 us; speedup vs baseline: 1.4666x; 1.0515x over previous
//
#include <hip/hip_runtime.h>

#define T_TOK 2048
#define NE 16
#define KTOP 4
#define HD 2048
#define ID 1408
#define SID 5632
#define CAPACITY 1024

typedef __attribute__((ext_vector_type(8))) short short8;   // 8 x bf16
typedef __attribute__((ext_vector_type(4))) float floatx4;  // MFMA acc

// fp32 -> bf16 round-to-nearest-even (scalar, epilogue use)
__device__ __forceinline__ short f2b(float f){
  union { float f; unsigned u; } v; v.f = f;
  unsigned r = v.u + 0x7fffu + ((v.u >> 16) & 1u);
  return (short)(r >> 16);
}
__device__ __forceinline__ float b2f(short s){
  union { float f; unsigned u; } v; v.u = ((unsigned)(unsigned short)s) << 16;
  return v.f;
}
// hardware packed fp32->bf16 RNE: lo halfword = a, hi halfword = b
__device__ __forceinline__ unsigned cvt_pk(float a, float b){
  unsigned r;
  asm("v_cvt_pk_bf16_f32 %0, %1, %2" : "=v"(r) : "v"(a), "v"(b));
  return r;
}
// convert 8 fp32 -> short8 (k-order preserved)
__device__ __forceinline__ short8 cvt8(float4 a, float4 b){
  union { unsigned d[4]; short8 s; } u;
  u.d[0] = cvt_pk(a.x, a.y); u.d[1] = cvt_pk(a.z, a.w);
  u.d[2] = cvt_pk(b.x, b.y); u.d[3] = cvt_pk(b.z, b.w);
  return u.s;
}
// async global->LDS, 16B per lane (wave-uniform LDS base + lane*16)
__device__ __forceinline__ void gl16(const void* g, void* l){
  __builtin_amdgcn_global_load_lds(
      (const __attribute__((address_space(1))) void*)g,
      (__attribute__((address_space(3))) void*)l, 16, 0, 0);
}

__global__ void moe_zero(int* __restrict__ counts){
  if (threadIdx.x < NE) counts[threadIdx.x] = 0;
}

// Router: fp32 logits -> d_out tail; softmax+top4; slot assignment via atomics
// (order-free: CAP = 2x mean load, drop prob ~0); x -> bf16; shared-gate sigmoid.
__global__ void moe_router(const float* __restrict__ x,
                           const float* __restrict__ gate_w,
                           const float* __restrict__ sg_w,
                           float* __restrict__ logits_out,
                           short* __restrict__ xb,
                           int* __restrict__ counts,
                           int* __restrict__ slot_token,
                           float* __restrict__ slot_w,
                           int* __restrict__ tslot,
                           float* __restrict__ tw,
                           float* __restrict__ sg)
{
  int wave = threadIdx.x >> 6, lane = threadIdx.x & 63;
  int t = (blockIdx.x << 2) + wave;
  if (t >= T_TOK) return;
  const float4* xr = (const float4*)(x + (size_t)t * HD);
  short8* xbw = (short8*)(xb + (size_t)t * HD);
  float acc[17];
  #pragma unroll
  for (int e = 0; e < 17; ++e) acc[e] = 0.f;
  #pragma unroll
  for (int j = 0; j < 4; ++j){
    int i4 = (j * 64 + lane) * 2;
    float4 x0 = xr[i4], x1 = xr[i4 + 1];
    xbw[j * 64 + lane] = cvt8(x0, x1);
    #pragma unroll
    for (int e = 0; e < 16; ++e){
      const float4* gr = (const float4*)(gate_w + e * HD);
      float4 g0 = gr[i4], g1 = gr[i4 + 1];
      acc[e] += x0.x*g0.x + x0.y*g0.y + x0.z*g0.z + x0.w*g0.w
              + x1.x*g1.x + x1.y*g1.y + x1.z*g1.z + x1.w*g1.w;
    }
    const float4* sr = (const float4*)sg_w;
    float4 s0 = sr[i4], s1 = sr[i4 + 1];
    acc[16] += x0.x*s0.x + x0.y*s0.y + x0.z*s0.z + x0.w*s0.w
             + x1.x*s1.x + x1.y*s1.y + x1.z*s1.z + x1.w*s1.w;
  }
  #pragma unroll
  for (int e = 0; e < 17; ++e){
    float v = acc[e];
    #pragma unroll
    for (int off = 32; off > 0; off >>= 1) v += __shfl_xor(v, off, 64);
    acc[e] = v;
  }
  if (lane == 0){
    float m = acc[0];
    #pragma unroll
    for (int e = 1; e < 16; ++e) m = fmaxf(m, acc[e]);
    float p[16]; float s = 0.f;
    #pragma unroll
    for (int e = 0; e < 16; ++e){ p[e] = expf(acc[e] - m); s += p[e]; }
    float inv = 1.f / s;
    #pragma unroll
    for (int e = 0; e < 16; ++e) logits_out[t * 16 + e] = acc[e];
    unsigned used = 0;
    for (int k = 0; k < KTOP; ++k){
      float best = -1.f; int bi = 0;
      #pragma unroll
      for (int e = 0; e < 16; ++e){
        float pe = ((used >> e) & 1u) ? -1.f : p[e];
        if (pe > best){ best = pe; bi = e; }
      }
      used |= (1u << bi);
      int pos = atomicAdd(&counts[bi], 1);
      int enc = -1;
      if (pos < CAPACITY){
        slot_token[bi * CAPACITY + pos] = t;
        slot_w[bi * CAPACITY + pos] = best * inv;
        enc = bi * CAPACITY + pos;
      }
      tslot[t * KTOP + k] = enc;
      tw[t * KTOP + k] = best * inv;
    }
    sg[t] = 1.f / (1.f + expf(-acc[16]));
  }
}

// ---------------------------------------------------------------------------
// GEMM tiles: BM=128, BK=64. LDS rows: 64 bf16 = 128B = 8 x 16B slots.
// Physical slot p of row r holds logical slot p ^ (r&7) (involution):
// A staged via global_load_lds from pre-swizzled bf16 addresses;
// B (fp32 weights) staged via regs: fp32 loads issued BEFORE the MFMA block,
// v_cvt_pk_bf16_f32 + ds_write_b128 into the NEXT buffer AFTER it (T14 split —
// HBM latency hides under MFMA; cvt is 16 ops/K-step, under the MFMA shadow).
// One __syncthreads per K-step (its vmcnt/lgkm drain is the phase boundary).
// Write-after-read safe: buf^1 was last read before the previous barrier.
// ---------------------------------------------------------------------------

// Fused gate+up GEMM: BN=64 per matrix, dual accumulators share the A tile.
__global__ __launch_bounds__(256) void moe_gateup(
    const short* __restrict__ Asrc,
    const float* __restrict__ Wg_, const float* __restrict__ Wu_,
    short* __restrict__ Out,
    const int* __restrict__ counts, const int* __restrict__ slot_token,
    int Ndim, int Kdim, int expert_mode, int mtiles, int ntiles)
{
  int nwg = gridDim.x;
  int wg = ((blockIdx.x & 7) * (nwg >> 3)) + (blockIdx.x >> 3);  // XCD swizzle
  int m_t = wg % mtiles; wg /= mtiles;
  int n_t = wg % ntiles; int e = wg / ntiles;

  int cnt = T_TOK; size_t woff = 0; short* out = Out;
  if (expert_mode){
    cnt = counts[e]; if (cnt > CAPACITY) cnt = CAPACITY;
    if (m_t * 128 >= cnt) return;
    woff = (size_t)e * Ndim * Kdim;
    out = Out + (size_t)e * CAPACITY * Ndim;
  }
  const int m0 = m_t * 128, n0 = n_t * 64;

  __shared__ __align__(16) char smem[2][32768];  // per buf: A 16K | Bg 8K | Bu 8K

  const int tid = threadIdx.x;
  const int lane = tid & 63, wave = tid >> 6;
  const int wr = wave >> 1, wc = wave & 1;
  const int lrow = lane & 15, lk = lane >> 4;

  const int srow = tid >> 3, pslot = tid & 7;
  const int lslot = pslot ^ (srow & 7);

  const short* aptr[4];
  #pragma unroll
  for (int i = 0; i < 4; ++i){
    int p = m0 + i * 32 + srow;
    const short* base;
    if (expert_mode){
      int q = (p < cnt) ? p : 0;
      base = Asrc + (size_t)slot_token[e * CAPACITY + q] * Kdim;
    } else base = Asrc + (size_t)p * Kdim;
    aptr[i] = base + (lslot << 3);
  }
  const float *bsrc[4];   // [0..1]=gate rows, [2..3]=up rows
  #pragma unroll
  for (int i = 0; i < 2; ++i){
    size_t roff = (size_t)(n0 + i * 32 + srow) * Kdim + (lslot << 3);
    bsrc[i]     = Wg_ + woff + roff;
    bsrc[i + 2] = Wu_ + woff + roff;
  }

  const floatx4 vzero = {0.f, 0.f, 0.f, 0.f};
  floatx4 accg[4][2], accu[4][2];
  #pragma unroll
  for (int i = 0; i < 4; ++i)
    #pragma unroll
    for (int j = 0; j < 2; ++j){ accg[i][j] = vzero; accu[i][j] = vzero; }

  const int fxor = lrow & 7;
  const int arowb = (wr * 64 + lrow) << 7;
  const int browb = (wc * 32 + lrow) << 7;
  const int bwoff = 16384 + (tid << 4);   // B ds_write target (Bg base)

  float4 breg[4][2];
  // prologue: stage K-step 0 into buf 0
  #pragma unroll
  for (int i = 0; i < 4; ++i) gl16(aptr[i], smem[0] + i * 4096 + tid * 16);
  #pragma unroll
  for (int i = 0; i < 4; ++i){
    breg[i][0] = *(const float4*)(bsrc[i]);
    breg[i][1] = *(const float4*)(bsrc[i] + 4);
  }
  #pragma unroll
  for (int i = 0; i < 4; ++i)
    *(short8*)(smem[0] + bwoff + i * 4096) = cvt8(breg[i][0], breg[i][1]);
  __syncthreads();

  int cur = 0;
  for (int k0 = 0; k0 < Kdim; k0 += 64){
    const bool more = (k0 + 64) < Kdim;
    if (more){
      #pragma unroll
      for (int i = 0; i < 4; ++i) gl16(aptr[i] + k0 + 64, smem[cur ^ 1] + i * 4096 + tid * 16);
      #pragma unroll
      for (int i = 0; i < 4; ++i){
        breg[i][0] = *(const float4*)(bsrc[i] + k0 + 64);
        breg[i][1] = *(const float4*)(bsrc[i] + k0 + 68);
      }
    }
    const char* bb = smem[cur];
    #pragma unroll
    for (int kh = 0; kh < 2; ++kh){
      const int soff = (((kh << 2) | lk) ^ fxor) << 4;
      short8 a[4], bg[2], bu[2];
      #pragma unroll
      for (int mf = 0; mf < 4; ++mf)
        a[mf] = *(const short8*)(bb + arowb + (mf << 11) + soff);
      #pragma unroll
      for (int nf = 0; nf < 2; ++nf){
        bg[nf] = *(const short8*)(bb + 16384 + browb + (nf << 11) + soff);
        bu[nf] = *(const short8*)(bb + 24576 + browb + (nf << 11) + soff);
      }
      #pragma unroll
      for (int mf = 0; mf < 4; ++mf)
        #pragma unroll
        for (int nf = 0; nf < 2; ++nf){
          accg[mf][nf] = __builtin_amdgcn_mfma_f32_16x16x32_bf16(a[mf], bg[nf], accg[mf][nf], 0, 0, 0);
          accu[mf][nf] = __builtin_amdgcn_mfma_f32_16x16x32_bf16(a[mf], bu[nf], accu[mf][nf], 0, 0, 0);
        }
    }
    if (more){
      #pragma unroll
      for (int i = 0; i < 4; ++i)
        *(short8*)(smem[cur ^ 1] + bwoff + i * 4096) = cvt8(breg[i][0], breg[i][1]);
    }
    __syncthreads();
    cur ^= 1;
  }

  // epilogue: SiLU(g)*u -> bf16. C/D: col = lane&15, row = 4*(lane>>4)+r
  const int colbase = n0 + wc * 32 + lrow;
  #pragma unroll
  for (int mf = 0; mf < 4; ++mf){
    int pr = m0 + wr * 64 + mf * 16 + lk * 4;
    #pragma unroll
    for (int nf = 0; nf < 2; ++nf){
      floatx4 g4 = accg[mf][nf], u4 = accu[mf][nf];
      int col = colbase + nf * 16;
      #pragma unroll
      for (int r = 0; r < 4; ++r){
        float gv = g4[r], uv = u4[r];
        float a = (gv / (1.f + __expf(-gv))) * uv;
        out[(size_t)(pr + r) * Ndim + col] = f2b(a);
      }
    }
  }
}

// Down GEMM. BN = NF*32 (NF=2 shared, NF=4 expert). Wave = 64 x (NF*16).
// expert: plain bf16 stores to eo (combine gathers later); atomic fallback if !eo.
// shared: y = sigmoid_gate * C (plain f32 stores, initializes y).
template<int NF>
__global__ __launch_bounds__(256) void moe_down(
    const short* __restrict__ Asrc, const float* __restrict__ Wd_,
    float* __restrict__ y, short* __restrict__ eo,
    const int* __restrict__ counts, const int* __restrict__ slot_token,
    const float* __restrict__ slot_w, const float* __restrict__ sgate,
    int Kdim, int expert_mode, int mtiles, int ntiles)
{
  constexpr int BN = NF * 32;
  int nwg = gridDim.x;
  int wg = ((blockIdx.x & 7) * (nwg >> 3)) + (blockIdx.x >> 3);
  int m_t = wg % mtiles; wg /= mtiles;
  int n_t = wg % ntiles; int e = wg / ntiles;

  int cnt = T_TOK; const short* ab = Asrc; size_t woff = 0;
  if (expert_mode){
    cnt = counts[e]; if (cnt > CAPACITY) cnt = CAPACITY;
    if (m_t * 128 >= cnt) return;
    ab = Asrc + (size_t)e * CAPACITY * Kdim;
    woff = (size_t)e * HD * Kdim;
  }
  const int m0 = m_t * 128, n0 = n_t * BN;

  __shared__ __align__(16) char smem[2][16384 + NF * 4096];

  const int tid = threadIdx.x;
  const int lane = tid & 63, wave = tid >> 6;
  const int wr = wave >> 1, wc = wave & 1;
  const int lrow = lane & 15, lk = lane >> 4;

  const int srow = tid >> 3, pslot = tid & 7;
  const int lslot = pslot ^ (srow & 7);

  const short* aptr[4];
  #pragma unroll
  for (int i = 0; i < 4; ++i)
    aptr[i] = ab + (size_t)(m0 + i * 32 + srow) * Kdim + (lslot << 3);
  const float* bsrc[NF];
  #pragma unroll
  for (int i = 0; i < NF; ++i)
    bsrc[i] = Wd_ + woff + (size_t)(n0 + i * 32 + srow) * Kdim + (lslot << 3);

  const floatx4 vzero = {0.f, 0.f, 0.f, 0.f};
  floatx4 acc[4][NF];
  #pragma unroll
  for (int i = 0; i < 4; ++i)
    #pragma unroll
    for (int j = 0; j < NF; ++j) acc[i][j] = vzero;

  const int fxor = lrow & 7;
  const int arowb = (wr * 64 + lrow) << 7;
  const int browb = (wc * (NF * 16) + lrow) << 7;
  const int bwoff = 16384 + (tid << 4);

  float4 breg[NF][2];
  #pragma unroll
  for (int i = 0; i < 4; ++i) gl16(aptr[i], smem[0] + i * 4096 + tid * 16);
  #pragma unroll
  for (int i = 0; i < NF; ++i){
    breg[i][0] = *(const float4*)(bsrc[i]);
    breg[i][1] = *(const float4*)(bsrc[i] + 4);
  }
  #pragma unroll
  for (int i = 0; i < NF; ++i)
    *(short8*)(smem[0] + bwoff + i * 4096) = cvt8(breg[i][0], breg[i][1]);
  __syncthreads();

  int cur = 0;
  for (int k0 = 0; k0 < Kdim; k0 += 64){
    const bool more = (k0 + 64) < Kdim;
    if (more){
      #pragma unroll
      for (int i = 0; i < 4; ++i) gl16(aptr[i] + k0 + 64, smem[cur ^ 1] + i * 4096 + tid * 16);
      #pragma unroll
      for (int i = 0; i < NF; ++i){
        breg[i][0] = *(const float4*)(bsrc[i] + k0 + 64);
        breg[i][1] = *(const float4*)(bsrc[i] + k0 + 68);
      }
    }
    const char* bb = smem[cur];
    #pragma unroll
    for (int kh = 0; kh < 2; ++kh){
      const int soff = (((kh << 2) | lk) ^ fxor) << 4;
      short8 a[4], b[NF];
      #pragma unroll
      for (int mf = 0; mf < 4; ++mf)
        a[mf] = *(const short8*)(bb + arowb + (mf << 11) + soff);
      #pragma unroll
      for (int nf = 0; nf < NF; ++nf)
        b[nf] = *(const short8*)(bb + 16384 + browb + (nf << 11) + soff);
      #pragma unroll
      for (int mf = 0; mf < 4; ++mf)
        #pragma unroll
        for (int nf = 0; nf < NF; ++nf)
          acc[mf][nf] = __builtin_amdgcn_mfma_f32_16x16x32_bf16(a[mf], b[nf], acc[mf][nf], 0, 0, 0);
    }
    if (more){
      #pragma unroll
      for (int i = 0; i < NF; ++i)
        *(short8*)(smem[cur ^ 1] + bwoff + i * 4096) = cvt8(breg[i][0], breg[i][1]);
    }
    __syncthreads();
    cur ^= 1;
  }

  const int colb = n0 + wc * (NF * 16) + lrow;
  if (expert_mode){
    if (eo){
      #pragma unroll
      for (int mf = 0; mf < 4; ++mf){
        int pr = m0 + wr * 64 + mf * 16 + lk * 4;
        #pragma unroll
        for (int r = 0; r < 4; ++r){
          int p = pr + r;
          #pragma unroll
          for (int nf = 0; nf < NF; ++nf)
            eo[(size_t)(e * CAPACITY + p) * HD + colb + nf * 16] = f2b(acc[mf][nf][r]);
        }
      }
    } else {
      #pragma unroll
      for (int mf = 0; mf < 4; ++mf){
        int pr = m0 + wr * 64 + mf * 16 + lk * 4;
        #pragma unroll
        for (int r = 0; r < 4; ++r){
          int p = pr + r;
          if (p < cnt){
            int tok = slot_token[e * CAPACITY + p];
            float w = slot_w[e * CAPACITY + p];
            #pragma unroll
            for (int nf = 0; nf < NF; ++nf)
              atomicAdd(&y[(size_t)tok * HD + colb + nf * 16], w * acc[mf][nf][r]);
          }
        }
      }
    }
  } else {
    #pragma unroll
    for (int mf = 0; mf < 4; ++mf){
      int pr = m0 + wr * 64 + mf * 16 + lk * 4;
      #pragma unroll
      for (int r = 0; r < 4; ++r){
        int t = pr + r;
        float sv = sgate[t];
        #pragma unroll
        for (int nf = 0; nf < NF; ++nf)
          y[(size_t)t * HD + colb + nf * 16] = sv * acc[mf][nf][r];
      }
    }
  }
}

// Gather-combine: y[t] += sum_k w_k * eo[slot_k]  (no atomics)
__global__ void moe_combine(const short* __restrict__ eo,
                            const int* __restrict__ tslot,
                            const float* __restrict__ tw,
                            float* __restrict__ y)
{
  int t = blockIdx.x;
  int o = threadIdx.x << 3;
  float* yp = y + (size_t)t * HD + o;
  float4 a0 = *(const float4*)yp, a1 = *(const float4*)(yp + 4);
  float acc[8] = {a0.x, a0.y, a0.z, a0.w, a1.x, a1.y, a1.z, a1.w};
  #pragma unroll
  for (int k = 0; k < KTOP; ++k){
    int s = tslot[t * KTOP + k];
    if (s >= 0){
      float w = tw[t * KTOP + k];
      short8 v = *(const short8*)(eo + (size_t)s * HD + o);
      #pragma unroll
      for (int j = 0; j < 8; ++j) acc[j] += w * b2f(v[j]);
    }
  }
  float4 r0 = {acc[0], acc[1], acc[2], acc[3]};
  float4 r1 = {acc[4], acc[5], acc[6], acc[7]};
  *(float4*)yp = r0; *(float4*)(yp + 4) = r1;
}

extern "C" void kernel_launch(void* const* d_in, const int* in_sizes, int n_in,
                              void* d_out, int out_size, void* d_ws, size_t ws_size,
                              hipStream_t stream)
{
  (void)in_sizes; (void)n_in; (void)out_size;
  const float* x       = (const float*)d_in[0];
  const float* gate_w  = (const float*)d_in[1];
  const float* we_gate = (const float*)d_in[2];
  const float* we_up   = (const float*)d_in[3];
  const float* we_down = (const float*)d_in[4];
  const float* wsg     = (const float*)d_in[5];
  const float* wsu     = (const float*)d_in[6];
  const float* wsd     = (const float*)d_in[7];
  const float* sg_w    = (const float*)d_in[8];

  float* y      = (float*)d_out;                 // [T, H]
  float* logits = y + (size_t)T_TOK * HD;        // [T, E]

  const size_t SZ_XB  = (size_t)T_TOK * HD * 2;          //  8.4 MB
  const size_t SZ_ACT = (size_t)NE * CAPACITY * ID * 2;  // 46.1 MB
  const size_t SZ_ACS = (size_t)T_TOK * SID * 2;         // 23.1 MB
  const size_t SZ_EO  = (size_t)NE * CAPACITY * HD * 2;  // 67.1 MB
  const size_t SZ_SMALL = 65536 + 65536 + 32768 + 32768 + 256 + 8192;

  const size_t NEED_B = SZ_XB + SZ_ACT + SZ_ACS + SZ_SMALL;
  const size_t NEED_A = NEED_B + SZ_EO;

  char* ws = (char*)d_ws;
  size_t off = 0;
  short* xb   = (short*)(ws + off); off += SZ_XB;
  short* act  = (short*)(ws + off); off += SZ_ACT;
  short* acts = (short*)(ws + off); off += SZ_ACS;
  short* eo   = (short*)(ws + off);
  if (ws_size >= NEED_A) off += SZ_EO; else eo = nullptr;
  int*   slot_token = (int*)  (ws + off); off += 65536;
  float* slot_w     = (float*)(ws + off); off += 65536;
  int*   tslot      = (int*)  (ws + off); off += 32768;
  float* tw         = (float*)(ws + off); off += 32768;
  int*   counts     = (int*)  (ws + off); off += 256;
  float* sg         = (float*)(ws + off);

  moe_zero<<<1, 64, 0, stream>>>(counts);
  moe_router<<<512, 256, 0, stream>>>(x, gate_w, sg_w, logits, xb,
                                      counts, slot_token, slot_w, tslot, tw, sg);
  // shared gate/up: M=2048 (16 mtiles), N=5632 (88 ntiles of 64), K=2048
  moe_gateup<<<16 * 88, 256, 0, stream>>>(xb, wsg, wsu, acts,
                                          nullptr, nullptr, SID, HD, 0, 16, 88);
  // expert gate/up: per-expert M<=1024 (8 mtiles), N=1408 (22 ntiles), K=2048
  moe_gateup<<<8 * 22 * NE, 256, 0, stream>>>(xb, we_gate, we_up, act,
                                              counts, slot_token, ID, HD, 1, 8, 22);
  // shared down: M=2048, N=2048 (32 ntiles of 64), K=5632
  moe_down<2><<<16 * 32, 256, 0, stream>>>(acts, wsd, y, nullptr, nullptr, nullptr,
                                           nullptr, sg, SID, 0, 16, 32);
  // expert down: M<=1024, N=2048 (16 ntiles of 128), K=1408
  moe_down<4><<<8 * 16 * NE, 256, 0, stream>>>(act, we_down, y, eo, counts, slot_token,
                                               slot_w, nullptr, ID, 1, 8, 16);
  if (eo) moe_combine<<<T_TOK, 256, 0, stream>>>(eo, tslot, tw, y);
}